// Round 1
// 451.261 us; speedup vs baseline: 1.0645x; 1.0645x over previous
//
#include <hip/hip_runtime.h>

// Two chained SAME 3x3 single-channel convs — register row-streaming, zero LDS.
//
// R2: the LDS-tile version was LDS-pipe-bound (bank conflicts alone = 36% of
// all CU cycles; LDS pipe ~63% busy) while HBM sat at 36% of peak. The op is
// only ~90 FMA per 4 outputs, so staging through LDS buys nothing. This
// version streams rows: each thread owns 4 columns, keeps a 2-row x window
// (8 floats/row) + a 3-row intermediate y window (6 floats/row) in registers,
// prefetches x[r+3] at the top of each iteration, and writes one coalesced
// float4 per row. No LDS, no barriers.
//
// Correctness: the second conv zero-pads the INTERMEDIATE y, so y row -1 /
// 2048 and y col -1 / 2048 are explicitly zeroed (NOT computed from padded x).
// x itself is zero-padded via the row guard (rin) and the le/re column guards.

#define IMG_H  2048
#define IMG_W  2048
#define RCHUNK 64          // z-rows per block
#define BLOCK  256         // threads; strip width = BLOCK*4 = 1024 cols

__global__ __launch_bounds__(BLOCK) void conv3x3x2_stream(
    const float* __restrict__ x,
    const float* __restrict__ w1,
    const float* __restrict__ w2,
    float* __restrict__ out,
    int B)
{
    const int tid = threadIdx.x;
    const int gc  = blockIdx.x * (BLOCK * 4) + tid * 4;  // owns cols gc..gc+3
    const int r0  = blockIdx.y * RCHUNK;
    const int b   = blockIdx.z;

    const float* xb = x   + (size_t)b * IMG_H * IMG_W;
    float*       ob = out + (size_t)b * IMG_H * IMG_W;

    float k1[9], k2[9];
#pragma unroll
    for (int i = 0; i < 9; ++i) { k1[i] = w1[i]; k2[i] = w2[i]; }

    const bool le = (gc == 0);            // left image edge lane
    const bool re = (gc == IMG_W - 4);    // right image edge lane

    // x window rows hold cols gc-2 .. gc+5 (8 floats)
    float xr0[8], xr1[8], xnew[8];
    // y rows hold cols gc-1 .. gc+4 (6 floats)
    float yA[6], yB[6], yC[6], yN[6];

    // Load x row `row_` cols gc-2..gc+5 into dst[0..7]; zeros outside image.
    // Strips are 1024-aligned and W%4==0, so OOB halo float4s are fully OOB.
#define LOADX(dst, row_)                                                    \
    {                                                                       \
        const int _r = (row_);                                              \
        const float4 _z4 = make_float4(0.f, 0.f, 0.f, 0.f);                 \
        float4 _va, _vb, _vc;                                               \
        if ((unsigned)_r < (unsigned)IMG_H) {                               \
            const float* _rp = xb + (size_t)_r * IMG_W;                     \
            _vb = *(const float4*)(_rp + gc);                               \
            _va = le ? _z4 : *(const float4*)(_rp + gc - 4);                \
            _vc = re ? _z4 : *(const float4*)(_rp + gc + 4);                \
        } else { _va = _z4; _vb = _z4; _vc = _z4; }                         \
        dst[0] = _va.z; dst[1] = _va.w;                                     \
        dst[2] = _vb.x; dst[3] = _vb.y; dst[4] = _vb.z; dst[5] = _vb.w;     \
        dst[6] = _vc.x; dst[7] = _vc.y;                                     \
    }

    // y[j] = conv1 at col gc-1+j, from x rows a_,b_,c_ (cols gc-2..gc+5).
    // Cols -1 / 2048 are conv2's zero padding -> zeroed on edge lanes.
#define COMPY(dst, a_, b_, c_)                                              \
    {                                                                       \
        _Pragma("unroll")                                                   \
        for (int j = 0; j < 6; ++j) {                                       \
            dst[j] = k1[0]*a_[j] + k1[1]*a_[j+1] + k1[2]*a_[j+2]            \
                   + k1[3]*b_[j] + k1[4]*b_[j+1] + k1[5]*b_[j+2]            \
                   + k1[6]*c_[j] + k1[7]*c_[j+1] + k1[8]*c_[j+2];           \
        }                                                                   \
        if (le) dst[0] = 0.f;                                               \
        if (re) dst[5] = 0.f;                                               \
    }

#define ZERO6(dst) { _Pragma("unroll") for (int _j = 0; _j < 6; ++_j) dst[_j] = 0.f; }

    // ---- prologue: yA=y[r0-1], yB=y[r0], yC=y[r0+1]; xr0=x[r0+1], xr1=x[r0+2]
    {
        float xa[8], xbv[8], xc[8];
        LOADX(xa,  r0 - 2);
        LOADX(xbv, r0 - 1);
        LOADX(xc,  r0);
        if (r0 >= 1) { COMPY(yA, xa, xbv, xc); } else { ZERO6(yA); }  // y[-1]=0
        LOADX(xa, r0 + 1);
        COMPY(yB, xbv, xc, xa);      // y[r0], always in-image
        LOADX(xbv, r0 + 2);
        COMPY(yC, xc, xa, xbv);      // y[r0+1], in-image since r0 <= H-RCHUNK
#pragma unroll
        for (int k = 0; k < 8; ++k) { xr0[k] = xa[k]; xr1[k] = xbv[k]; }
    }

    // ---- main loop: one z row per iteration ----
    // Invariant at top of iter t (r=r0+t): yA=y[r-1+1-1]... yA=y[r-1], yB=y[r],
    // yC=y[r+1] ready; xr0=x[r+1], xr1=x[r+2].
#pragma unroll 4
    for (int t = 0; t < RCHUNK; ++t) {
        const int r = r0 + t;

        // prefetch x[r+3] (consumed after the z-compute below)
        LOADX(xnew, r + 3);

        // z row r from yA,yB,yC (cols gc..gc+3)
        float s[4];
#pragma unroll
        for (int i = 0; i < 4; ++i) {
            s[i] = k2[0]*yA[i] + k2[1]*yA[i+1] + k2[2]*yA[i+2]
                 + k2[3]*yB[i] + k2[4]*yB[i+1] + k2[5]*yB[i+2]
                 + k2[6]*yC[i] + k2[7]*yC[i+1] + k2[8]*yC[i+2];
        }
        *(float4*)(ob + (size_t)r * IMG_W + gc) = make_float4(s[0], s[1], s[2], s[3]);

        // y[r+2] for next iteration; zero outside image (conv2 padding)
        if (r + 2 < IMG_H) { COMPY(yN, xr0, xr1, xnew); } else { ZERO6(yN); }

        // shift windows (renamed away by the unroll)
#pragma unroll
        for (int j = 0; j < 6; ++j) { yA[j] = yB[j]; yB[j] = yC[j]; yC[j] = yN[j]; }
#pragma unroll
        for (int k = 0; k < 8; ++k) { xr0[k] = xr1[k]; xr1[k] = xnew[k]; }
    }

#undef LOADX
#undef COMPY
#undef ZERO6
}

extern "C" void kernel_launch(void* const* d_in, const int* in_sizes, int n_in,
                              void* d_out, int out_size, void* d_ws, size_t ws_size,
                              hipStream_t stream) {
    const float* x  = (const float*)d_in[0];
    const float* w1 = (const float*)d_in[1];
    const float* w2 = (const float*)d_in[2];
    float* out = (float*)d_out;
    int B = in_sizes[0] / (IMG_H * IMG_W);
    dim3 grid(IMG_W / (BLOCK * 4), IMG_H / RCHUNK, B);
    conv3x3x2_stream<<<grid, dim3(BLOCK, 1, 1), 0, stream>>>(x, w1, w2, out, B);
}